// Round 6
// baseline (333.168 us; speedup 1.0000x reference)
//
#include <hip/hip_runtime.h>
#include <hip/hip_bf16.h>

#define SEGS   16384
#define DCH    128
#define CHUNK  32
#define SEGPB  4          // consecutive segments per block
#define PSH    128        // plane pitch in shorts (256B row, XOR-swizzled)
#define LOG2E  1.4426950408889634f

using f32x4  = __attribute__((ext_vector_type(4))) float;
using bf16x8 = __attribute__((ext_vector_type(8))) short;
using u32x2  = __attribute__((ext_vector_type(2))) unsigned int;
using u32x4  = __attribute__((ext_vector_type(4))) unsigned int;

__device__ __forceinline__ float u2f(unsigned int u) { return __uint_as_float(u); }
__device__ __forceinline__ unsigned int f2u(float f) { return __float_as_uint(f); }
// swizzled short-index: spreads rows across bank groups (m214 recipe, 16B grain)
__device__ __forceinline__ int swz(int row, int col) {
  return row * PSH + (col ^ ((row & 7) << 3));
}

// ---------------------------------------------------------------------------
// Setup: (a) W' = W * log2e -> fragment-ready bf16 hi/lo B-operand layout
//        (b) per-segment row starts via binary search on sorted index
// ---------------------------------------------------------------------------
__global__ void setup_kernel(const float* __restrict__ W,
                             const int* __restrict__ index, int N,
                             unsigned short* __restrict__ WfH,
                             unsigned short* __restrict__ WfL,
                             int* __restrict__ seg_start) {
  int i = blockIdx.x * blockDim.x + threadIdx.x;
  if (i < DCH * DCH) {
    int n = i >> 7, k = i & 127;           // W[n][k]
    float w = W[i] * LOG2E;                // fold log2e -> raw exp2 in softmax
    unsigned int u = f2u(w);
    unsigned int hu = u & 0xFFFF0000u;     // truncated bf16 hi
    float lo = w - u2f(hu);                // residual -> bf16 lo
    int kt    = k >> 5;
    int ntile = n >> 4;
    int lane  = (n & 15) + 16 * ((k >> 3) & 3);
    int j     = k & 7;
    int dst = ((kt * 8 + ntile) * 64 + lane) * 8 + j;
    WfH[dst] = (unsigned short)(u >> 16);
    WfL[dst] = (unsigned short)(f2u(lo) >> 16);
  } else if (i < DCH * DCH + SEGS + 1) {
    int s = i - DCH * DCH;                 // lower_bound(index, s)
    int lo = 0, hi = N;
    while (lo < hi) {
      int mid = (lo + hi) >> 1;
      if (index[mid] < s) lo = mid + 1; else hi = mid;
    }
    seg_start[s] = lo;
  }
}

// ---------------------------------------------------------------------------
// Main: block b owns segments [4b, 4b+4). 4 waves; wave w owns channels
// [32w, 32w+32). 2-buffer LDS pipeline, one raw s_barrier per chunk; next
// chunk's global loads stay in flight across the barrier. LDS planes are
// XOR-swizzled (conflict-free b128/b64). The e*x phase transposes p within
// lane quads so xh/xl reads are vectorized ds_read_b64.
// ---------------------------------------------------------------------------
__global__ __launch_bounds__(256) void pool_kernel(
    const float* __restrict__ x, const float* __restrict__ bias,
    const int* __restrict__ seg_start,
    const u32x4* __restrict__ WfH, const u32x4* __restrict__ WfL,
    float* __restrict__ out) {
  __shared__ unsigned short xh[2][CHUNK * PSH];
  __shared__ unsigned short xl[2][CHUNK * PSH];

  const int t    = threadIdx.x;
  const int wv   = t >> 6;
  const int lane = t & 63;
  const int cl   = lane & 15;              // A-row sel / C col within 16-tile
  const int g    = lane >> 4;              // lane group (k-slice / row group)
  const int qi   = lane & 3;               // quad pos (row select after transpose)
  const int lrow = t >> 5;                 // staging: rows 0..7 (+8 per p)
  const int lcol = (t & 31) << 2;          // staging: col (4-float quad)

  // Register-resident B fragments (this wave's 32 channels), hi & lo — once.
  u32x4 bh[4][2], bl[4][2];
#pragma unroll
  for (int kt = 0; kt < 4; ++kt)
#pragma unroll
    for (int nt = 0; nt < 2; ++nt) {
      int off = (kt * 8 + (wv * 2 + nt)) * 64 + lane;   // 16B units
      bh[kt][nt] = WfH[off];
      bl[kt][nt] = WfL[off];
    }

  const float bc0 = bias[wv * 32 + cl]      * LOG2E;
  const float bc1 = bias[wv * 32 + 16 + cl] * LOG2E;

  const int s0   = blockIdx.x * SEGPB;
  const int sEnd = s0 + SEGPB;

  // Empty segments (rare): write zeros outside the pipeline, keep CF uniform.
  for (int es = s0; es < sEnd; ++es) {
    if (seg_start[es + 1] == seg_start[es] && lane < 16) {
      out[(size_t)es * DCH + wv * 32 + cl]      = 0.f;
      out[(size_t)es * DCH + wv * 32 + 16 + cl] = 0.f;
    }
  }

  int s = s0;
  while (s < sEnd && seg_start[s + 1] == seg_start[s]) ++s;
  if (s >= sEnd) return;                   // whole block empty (uniform exit)

  int c0  = 0;
  int len = seg_start[s + 1] - seg_start[s];
  int cnt = (len < CHUNK) ? len : CHUNK;

  // Prefetch first chunk into registers (rows >= cnt zero-filled).
  f32x4 pv[4];
  {
    const int base = seg_start[s];
#pragma unroll
    for (int p = 0; p < 4; ++p) {
      int lr = lrow + p * 8;
      f32x4 v = {0.f, 0.f, 0.f, 0.f};
      if (lr < cnt) v = *(const f32x4*)(x + (size_t)(base + lr) * DCH + lcol);
      pv[p] = v;
    }
  }

  f32x4 num_v[2], den_v[2];
#pragma unroll
  for (int nt = 0; nt < 2; ++nt) {
    num_v[nt] = (f32x4){0.f, 0.f, 0.f, 0.f};
    den_v[nt] = (f32x4){0.f, 0.f, 0.f, 0.f};
  }
  int buf = 0;

  while (true) {
    // ---- next-chunk coordinates (wave-uniform scalar work) ----
    int ns = s, nc0 = c0 + CHUNK;
    if (nc0 >= len) {
      nc0 = 0; ns = s + 1;
      while (ns < sEnd && seg_start[ns + 1] == seg_start[ns]) ++ns;
    }
    const bool have_next = (ns < sEnd);
    int nlen = 0, ncnt = 0, nbase = 0;
    if (have_next) {
      nbase = seg_start[ns] + nc0;
      nlen  = seg_start[ns + 1] - seg_start[ns];
      ncnt  = nlen - nc0; if (ncnt > CHUNK) ncnt = CHUNK;
    }

    // ---- convert prefetched regs -> swizzled LDS planes (vmcnt wait here) --
    unsigned short* XH = &xh[buf][0];
    unsigned short* XL = &xl[buf][0];
#pragma unroll
    for (int p = 0; p < 4; ++p) {
      int lr = lrow + p * 8;
      f32x4 v = pv[p];
      unsigned int u0 = f2u(v[0]), u1 = f2u(v[1]), u2 = f2u(v[2]), u3 = f2u(v[3]);
      unsigned int h0 = u0 & 0xFFFF0000u, h1 = u1 & 0xFFFF0000u;
      unsigned int h2 = u2 & 0xFFFF0000u, h3 = u3 & 0xFFFF0000u;
      float l0f = v[0] - u2f(h0), l1f = v[1] - u2f(h1);
      float l2f = v[2] - u2f(h2), l3f = v[3] - u2f(h3);
      u32x2 H = { h1 | (u0 >> 16), h3 | (u2 >> 16) };
      u32x2 L = { (f2u(l1f) & 0xFFFF0000u) | (f2u(l0f) >> 16),
                  (f2u(l3f) & 0xFFFF0000u) | (f2u(l2f) >> 16) };
      int di = swz(lr, lcol);
      *(u32x2*)&XH[di] = H;
      *(u32x2*)&XL[di] = L;
    }

    // ---- issue next chunk's global loads (in flight through MFMA phase) ----
    if (have_next) {
#pragma unroll
      for (int p = 0; p < 4; ++p) {
        int lr = lrow + p * 8;
        f32x4 v = {0.f, 0.f, 0.f, 0.f};
        if (lr < ncnt) v = *(const f32x4*)(x + (size_t)(nbase + lr) * DCH + lcol);
        pv[p] = v;
      }
    }

    // ---- single barrier: planes of buf ready; prefetch NOT drained ----
    asm volatile("s_waitcnt lgkmcnt(0)" ::: "memory");
    __builtin_amdgcn_sched_barrier(0);
    __builtin_amdgcn_s_barrier();
    __builtin_amdgcn_sched_barrier(0);

    // ---- att' = (x @ W'^T + b') for this chunk (this wave's 32 cols) ----
    f32x4 Cf[2][2];
#pragma unroll
    for (int mt = 0; mt < 2; ++mt) {
      Cf[mt][0] = (f32x4){bc0, bc0, bc0, bc0};
      Cf[mt][1] = (f32x4){bc1, bc1, bc1, bc1};
    }

#pragma unroll
    for (int kt = 0; kt < 4; ++kt) {
      u32x4 ah[2], al[2];
#pragma unroll
      for (int mt = 0; mt < 2; ++mt) {
        int ai = swz(mt * 16 + cl, kt * 32 + g * 8);
        ah[mt] = *(const u32x4*)&XH[ai];
        al[mt] = *(const u32x4*)&XL[ai];
      }
#pragma unroll
      for (int sp = 0; sp < 3; ++sp)       // hh, hl, lh
#pragma unroll
        for (int mt = 0; mt < 2; ++mt)
#pragma unroll
          for (int nt = 0; nt < 2; ++nt) {
            bf16x8 A = __builtin_bit_cast(bf16x8, (sp == 2) ? al[mt] : ah[mt]);
            bf16x8 B = __builtin_bit_cast(bf16x8, (sp == 1) ? bl[kt][nt] : bh[kt][nt]);
            Cf[mt][nt] = __builtin_amdgcn_mfma_f32_16x16x32_bf16(A, B, Cf[mt][nt], 0, 0, 0);
          }
    }

    // ---- e = exp2(att'); quad-transpose p; vectorized e*x accumulate ----
    // C layout: col = lane&15, row(in 16-tile) = g*4 + reg   [m89/m91]
#pragma unroll
    for (int nt = 0; nt < 2; ++nt) {
      const int cb = wv * 32 + nt * 16 + (cl & ~3);
#pragma unroll
      for (int mt = 0; mt < 2; ++mt) {
        float p0 = __builtin_amdgcn_exp2f(Cf[mt][nt][0]);
        float p1 = __builtin_amdgcn_exp2f(Cf[mt][nt][1]);
        float p2 = __builtin_amdgcn_exp2f(Cf[mt][nt][2]);
        float p3 = __builtin_amdgcn_exp2f(Cf[mt][nt][3]);
        // 4x4 transpose within the lane quad (rows<->quad lanes)
        { float sv = (lane & 1) ? p0 : p1; float rv = __shfl_xor(sv, 1);
          if (lane & 1) p0 = rv; else p1 = rv; }
        { float sv = (lane & 1) ? p2 : p3; float rv = __shfl_xor(sv, 1);
          if (lane & 1) p2 = rv; else p3 = rv; }
        { float sv = (lane & 2) ? p0 : p2; float rv = __shfl_xor(sv, 2);
          if (lane & 2) p0 = rv; else p2 = rv; }
        { float sv = (lane & 2) ? p1 : p3; float rv = __shfl_xor(sv, 2);
          if (lane & 2) p1 = rv; else p3 = rv; }
        // lane now holds row (mt*16+g*4+qi), cols cb..cb+3
        const int row = mt * 16 + g * 4 + qi;
        if (row < cnt) {
          const int di = swz(row, cb);
          u32x2 hv = *(const u32x2*)&XH[di];
          u32x2 lv = *(const u32x2*)&XL[di];
          float x0 = u2f(hv[0] << 16)          + u2f(lv[0] << 16);
          float x1 = u2f(hv[0] & 0xFFFF0000u)  + u2f(lv[0] & 0xFFFF0000u);
          float x2 = u2f(hv[1] << 16)          + u2f(lv[1] << 16);
          float x3 = u2f(hv[1] & 0xFFFF0000u)  + u2f(lv[1] & 0xFFFF0000u);
          den_v[nt][0] += p0; num_v[nt][0] += p0 * x0;
          den_v[nt][1] += p1; num_v[nt][1] += p1 * x1;
          den_v[nt][2] += p2; num_v[nt][2] += p2 * x2;
          den_v[nt][3] += p3; num_v[nt][3] += p3 * x3;
        }
      }
    }

    // ---- segment bookkeeping ----
    if (c0 + CHUNK >= len) {               // segment s complete -> store
#pragma unroll
      for (int nt = 0; nt < 2; ++nt) {
        f32x4 a = num_v[nt], l = den_v[nt];
#pragma unroll
        for (int c = 0; c < 4; ++c) {
          a[c] += __shfl_xor(a[c], 1);  l[c] += __shfl_xor(l[c], 1);
          a[c] += __shfl_xor(a[c], 2);  l[c] += __shfl_xor(l[c], 2);
          a[c] += __shfl_xor(a[c], 16); l[c] += __shfl_xor(l[c], 16);
          a[c] += __shfl_xor(a[c], 32); l[c] += __shfl_xor(l[c], 32);
        }
        if (lane < 16) {
          float av = (qi == 0) ? a[0] : (qi == 1) ? a[1] : (qi == 2) ? a[2] : a[3];
          float lv2 = (qi == 0) ? l[0] : (qi == 1) ? l[1] : (qi == 2) ? l[2] : l[3];
          out[(size_t)s * DCH + wv * 32 + nt * 16 + cl] = av / (lv2 + 1e-16f);
        }
        num_v[nt] = (f32x4){0.f, 0.f, 0.f, 0.f};
        den_v[nt] = (f32x4){0.f, 0.f, 0.f, 0.f};
      }
      if (!have_next) break;
      s = ns; len = nlen; c0 = 0;
    } else {
      c0 = nc0;
    }
    cnt = ncnt;
    buf ^= 1;
  }
}

extern "C" void kernel_launch(void* const* d_in, const int* in_sizes, int n_in,
                              void* d_out, int out_size, void* d_ws, size_t ws_size,
                              hipStream_t stream) {
  const float* x    = (const float*)d_in[0];
  const float* W    = (const float*)d_in[1];
  const float* bias = (const float*)d_in[2];
  const int*   idx  = (const int*)d_in[3];
  const int N = in_sizes[0] / DCH;

  unsigned short* WfH = (unsigned short*)d_ws;            // 32 KB
  unsigned short* WfL = WfH + DCH * DCH;                  // 32 KB
  int* seg = (int*)(WfL + DCH * DCH);                     // (SEGS+1)*4 B

  int setup_threads = DCH * DCH + SEGS + 1;
  setup_kernel<<<(setup_threads + 255) / 256, 256, 0, stream>>>(W, idx, N, WfH, WfL, seg);
  pool_kernel<<<SEGS / SEGPB, 256, 0, stream>>>(x, bias, seg,
                                                (const u32x4*)WfH, (const u32x4*)WfL,
                                                (float*)d_out);
}

// Round 7
// 312.925 us; speedup vs baseline: 1.0647x; 1.0647x over previous
//
#include <hip/hip_runtime.h>
#include <hip/hip_bf16.h>

#define SEGS   16384
#define DCH    128
#define CHUNK  32
#define SEGPB  4          // consecutive segments per block
#define PSH    128        // plane pitch in shorts (256B row)
#define LOG2E  1.4426950408889634f

using f32x4  = __attribute__((ext_vector_type(4))) float;
using bf16x8 = __attribute__((ext_vector_type(8))) short;
using u32x2  = __attribute__((ext_vector_type(2))) unsigned int;
using u32x4  = __attribute__((ext_vector_type(4))) unsigned int;

__device__ __forceinline__ float u2f(unsigned int u) { return __uint_as_float(u); }
__device__ __forceinline__ unsigned int f2u(float f) { return __float_as_uint(f); }
// bijective 16-row swizzle at 16B grain: 16 rows -> 16 distinct chunks
__device__ __forceinline__ int swz(int row, int col) {
  return row * PSH + (col ^ ((row & 15) << 3));
}

// ---------------------------------------------------------------------------
// Setup: (a) W' = W * log2e -> fragment-ready bf16 hi/lo layout (serves as the
//            MFMA *A* operand: lane = (ch&15) + 16*kgrp holds 8 consecutive k)
//        (b) per-segment row starts via binary search on sorted index
// ---------------------------------------------------------------------------
__global__ void setup_kernel(const float* __restrict__ W,
                             const int* __restrict__ index, int N,
                             unsigned short* __restrict__ WfH,
                             unsigned short* __restrict__ WfL,
                             int* __restrict__ seg_start) {
  int i = blockIdx.x * blockDim.x + threadIdx.x;
  if (i < DCH * DCH) {
    int n = i >> 7, k = i & 127;           // W[n][k], n = channel
    float w = W[i] * LOG2E;                // fold log2e -> raw exp2 in softmax
    unsigned int u = f2u(w);
    unsigned int hu = u & 0xFFFF0000u;     // truncated bf16 hi
    float lo = w - u2f(hu);                // residual -> bf16 lo
    int kt    = k >> 5;
    int ntile = n >> 4;
    int lane  = (n & 15) + 16 * ((k >> 3) & 3);
    int j     = k & 7;
    int dst = ((kt * 8 + ntile) * 64 + lane) * 8 + j;
    WfH[dst] = (unsigned short)(u >> 16);
    WfL[dst] = (unsigned short)(f2u(lo) >> 16);
  } else if (i < DCH * DCH + SEGS + 1) {
    int s = i - DCH * DCH;                 // lower_bound(index, s)
    int lo = 0, hi = N;
    while (lo < hi) {
      int mid = (lo + hi) >> 1;
      if (index[mid] < s) lo = mid + 1; else hi = mid;
    }
    seg_start[s] = lo;
  }
}

// ---------------------------------------------------------------------------
// Main: block b owns segments [4b, 4b+4). 4 waves; wave w owns channels
// [32w, 32w+32). 2-buffer LDS pipeline, one raw s_barrier per chunk; next
// chunk's global loads stay in flight across the barrier.
// SWAPPED MFMA: A = W' (channels x k), B = x^T (k x rows) => C[ch][row] with
// col(lane&15) = x-row, regs = 4 consecutive channels. e*x is then a plain
// vectorized row-major LDS read — no transpose, no scalar reads.
// ---------------------------------------------------------------------------
__global__ __launch_bounds__(256) void pool_kernel(
    const float* __restrict__ x, const float* __restrict__ bias,
    const int* __restrict__ seg_start,
    const u32x4* __restrict__ WfH, const u32x4* __restrict__ WfL,
    float* __restrict__ out) {
  __shared__ unsigned short xh[2][CHUNK * PSH];
  __shared__ unsigned short xl[2][CHUNK * PSH];

  const int t    = threadIdx.x;
  const int wv   = t >> 6;
  const int lane = t & 63;
  const int cl   = lane & 15;              // x-row within 16-tile (C col)
  const int g    = lane >> 4;              // k-group / channel-quad select
  const int lrow = t >> 5;                 // staging: rows 0..7 (+8 per p)
  const int lcol = (t & 31) << 2;          // staging: element col (4-aligned)

  // W' fragments (A operand) for this wave's 32 channels, hi & lo — once.
  u32x4 wh[4][2], wl[4][2];
#pragma unroll
  for (int kt = 0; kt < 4; ++kt)
#pragma unroll
    for (int mt = 0; mt < 2; ++mt) {
      int off = (kt * 8 + (wv * 2 + mt)) * 64 + lane;   // 16B units
      wh[kt][mt] = WfH[off];
      wl[kt][mt] = WfL[off];
    }

  // bias for this lane's 4 channels per mt (broadcast over cl)
  f32x4 bias_v[2];
#pragma unroll
  for (int mt = 0; mt < 2; ++mt) {
    f32x4 b = *(const f32x4*)&bias[wv * 32 + mt * 16 + g * 4];
#pragma unroll
    for (int c = 0; c < 4; ++c) bias_v[mt][c] = b[c] * LOG2E;
  }

  const int s0   = blockIdx.x * SEGPB;
  const int sEnd = s0 + SEGPB;

  // Empty segments (rare): zeros, outside the pipeline.
  for (int es = s0; es < sEnd; ++es) {
    if (seg_start[es + 1] == seg_start[es] && cl == 0) {
#pragma unroll
      for (int mt = 0; mt < 2; ++mt)
        *(f32x4*)&out[(size_t)es * DCH + wv * 32 + mt * 16 + g * 4] =
            (f32x4){0.f, 0.f, 0.f, 0.f};
    }
  }

  int s = s0;
  while (s < sEnd && seg_start[s + 1] == seg_start[s]) ++s;
  if (s >= sEnd) return;                   // whole block empty (uniform exit)

  int c0  = 0;
  int len = seg_start[s + 1] - seg_start[s];
  int cnt = (len < CHUNK) ? len : CHUNK;

  // Prefetch first chunk into registers (rows >= cnt zero-filled).
  f32x4 pv[4];
  {
    const int base = seg_start[s];
#pragma unroll
    for (int p = 0; p < 4; ++p) {
      int lr = lrow + p * 8;
      f32x4 v = {0.f, 0.f, 0.f, 0.f};
      if (lr < cnt) v = *(const f32x4*)(x + (size_t)(base + lr) * DCH + lcol);
      pv[p] = v;
    }
  }

  f32x4 num_v[2], den_v[2];                // [mt], elements = 4 channels (r)
#pragma unroll
  for (int mt = 0; mt < 2; ++mt) {
    num_v[mt] = (f32x4){0.f, 0.f, 0.f, 0.f};
    den_v[mt] = (f32x4){0.f, 0.f, 0.f, 0.f};
  }
  int buf = 0;

  while (true) {
    // ---- next-chunk coordinates (wave-uniform scalar work) ----
    int ns = s, nc0 = c0 + CHUNK;
    if (nc0 >= len) {
      nc0 = 0; ns = s + 1;
      while (ns < sEnd && seg_start[ns + 1] == seg_start[ns]) ++ns;
    }
    const bool have_next = (ns < sEnd);
    int nlen = 0, ncnt = 0, nbase = 0;
    if (have_next) {
      nbase = seg_start[ns] + nc0;
      nlen  = seg_start[ns + 1] - seg_start[ns];
      ncnt  = nlen - nc0; if (ncnt > CHUNK) ncnt = CHUNK;
    }

    // ---- convert prefetched regs -> swizzled LDS planes (vmcnt wait here) --
    unsigned short* XH = &xh[buf][0];
    unsigned short* XL = &xl[buf][0];
#pragma unroll
    for (int p = 0; p < 4; ++p) {
      int lr = lrow + p * 8;
      f32x4 v = pv[p];
      unsigned int u0 = f2u(v[0]), u1 = f2u(v[1]), u2 = f2u(v[2]), u3 = f2u(v[3]);
      unsigned int h0 = u0 & 0xFFFF0000u, h1 = u1 & 0xFFFF0000u;
      unsigned int h2 = u2 & 0xFFFF0000u, h3 = u3 & 0xFFFF0000u;
      float l0f = v[0] - u2f(h0), l1f = v[1] - u2f(h1);
      float l2f = v[2] - u2f(h2), l3f = v[3] - u2f(h3);
      u32x2 H = { h1 | (u0 >> 16), h3 | (u2 >> 16) };
      u32x2 L = { (f2u(l1f) & 0xFFFF0000u) | (f2u(l0f) >> 16),
                  (f2u(l3f) & 0xFFFF0000u) | (f2u(l2f) >> 16) };
      int di = swz(lr, lcol);
      *(u32x2*)&XH[di] = H;
      *(u32x2*)&XL[di] = L;
    }

    // ---- issue next chunk's global loads (in flight through MFMA phase) ----
    if (have_next) {
#pragma unroll
      for (int p = 0; p < 4; ++p) {
        int lr = lrow + p * 8;
        f32x4 v = {0.f, 0.f, 0.f, 0.f};
        if (lr < ncnt) v = *(const f32x4*)(x + (size_t)(nbase + lr) * DCH + lcol);
        pv[p] = v;
      }
    }

    // ---- single barrier: planes of buf ready; prefetch NOT drained ----
    asm volatile("s_waitcnt lgkmcnt(0)" ::: "memory");
    __builtin_amdgcn_sched_barrier(0);
    __builtin_amdgcn_s_barrier();
    __builtin_amdgcn_sched_barrier(0);

    // ---- att'^T = W' x^T + b' : C[ch][row], this wave's 32 channels ----
    f32x4 Cf[2][2];                        // [mt(ch)][nt(row)]
#pragma unroll
    for (int mt = 0; mt < 2; ++mt)
#pragma unroll
      for (int nt = 0; nt < 2; ++nt)
        Cf[mt][nt] = bias_v[mt];

#pragma unroll
    for (int kt = 0; kt < 4; ++kt) {
      u32x4 xbh[2], xbl[2];                // x^T B-frags per nt (row tile)
#pragma unroll
      for (int nt = 0; nt < 2; ++nt) {
        int ai = swz(nt * 16 + cl, kt * 32 + g * 8);
        xbh[nt] = *(const u32x4*)&XH[ai];
        xbl[nt] = *(const u32x4*)&XL[ai];
      }
#pragma unroll
      for (int sp = 0; sp < 3; ++sp)       // (Wh,xh), (Wl,xh), (Wh,xl)
#pragma unroll
        for (int mt = 0; mt < 2; ++mt)
#pragma unroll
          for (int nt = 0; nt < 2; ++nt) {
            bf16x8 A = __builtin_bit_cast(bf16x8, (sp == 1) ? wl[kt][mt] : wh[kt][mt]);
            bf16x8 B = __builtin_bit_cast(bf16x8, (sp == 2) ? xbl[nt] : xbh[nt]);
            Cf[mt][nt] = __builtin_amdgcn_mfma_f32_16x16x32_bf16(A, B, Cf[mt][nt], 0, 0, 0);
          }
    }

    // ---- e = exp2(att'); vectorized e*x accumulate (all lane-local) ----
    // C layout: col(lane&15) = x-row, reg r = channel mt*16 + g*4 + r
#pragma unroll
    for (int nt = 0; nt < 2; ++nt) {
      const int row = nt * 16 + cl;
      if (row < cnt) {
#pragma unroll
        for (int mt = 0; mt < 2; ++mt) {
          const int di = swz(row, wv * 32 + mt * 16 + g * 4);
          u32x2 hv = *(const u32x2*)&XH[di];
          u32x2 lv = *(const u32x2*)&XL[di];
          float x0 = u2f(hv[0] << 16)         + u2f(lv[0] << 16);
          float x1 = u2f(hv[0] & 0xFFFF0000u) + u2f(lv[0] & 0xFFFF0000u);
          float x2 = u2f(hv[1] << 16)         + u2f(lv[1] << 16);
          float x3 = u2f(hv[1] & 0xFFFF0000u) + u2f(lv[1] & 0xFFFF0000u);
          float p0 = __builtin_amdgcn_exp2f(Cf[mt][nt][0]);
          float p1 = __builtin_amdgcn_exp2f(Cf[mt][nt][1]);
          float p2 = __builtin_amdgcn_exp2f(Cf[mt][nt][2]);
          float p3 = __builtin_amdgcn_exp2f(Cf[mt][nt][3]);
          den_v[mt][0] += p0; num_v[mt][0] += p0 * x0;
          den_v[mt][1] += p1; num_v[mt][1] += p1 * x1;
          den_v[mt][2] += p2; num_v[mt][2] += p2 * x2;
          den_v[mt][3] += p3; num_v[mt][3] += p3 * x3;
        }
      }
    }

    // ---- segment bookkeeping ----
    if (c0 + CHUNK >= len) {               // segment s complete -> store
#pragma unroll
      for (int mt = 0; mt < 2; ++mt) {
#pragma unroll
        for (int c = 0; c < 4; ++c) {      // butterfly over cl (rows)
          num_v[mt][c] += __shfl_xor(num_v[mt][c], 1);
          den_v[mt][c] += __shfl_xor(den_v[mt][c], 1);
          num_v[mt][c] += __shfl_xor(num_v[mt][c], 2);
          den_v[mt][c] += __shfl_xor(den_v[mt][c], 2);
          num_v[mt][c] += __shfl_xor(num_v[mt][c], 4);
          den_v[mt][c] += __shfl_xor(den_v[mt][c], 4);
          num_v[mt][c] += __shfl_xor(num_v[mt][c], 8);
          den_v[mt][c] += __shfl_xor(den_v[mt][c], 8);
        }
        if (cl == 0) {
          f32x4 o;
#pragma unroll
          for (int c = 0; c < 4; ++c) o[c] = num_v[mt][c] / (den_v[mt][c] + 1e-16f);
          *(f32x4*)&out[(size_t)s * DCH + wv * 32 + mt * 16 + g * 4] = o;
        }
        num_v[mt] = (f32x4){0.f, 0.f, 0.f, 0.f};
        den_v[mt] = (f32x4){0.f, 0.f, 0.f, 0.f};
      }
      if (!have_next) break;
      s = ns; len = nlen; c0 = 0;
    } else {
      c0 = nc0;
    }
    cnt = ncnt;
    buf ^= 1;
  }
}

extern "C" void kernel_launch(void* const* d_in, const int* in_sizes, int n_in,
                              void* d_out, int out_size, void* d_ws, size_t ws_size,
                              hipStream_t stream) {
  const float* x    = (const float*)d_in[0];
  const float* W    = (const float*)d_in[1];
  const float* bias = (const float*)d_in[2];
  const int*   idx  = (const int*)d_in[3];
  const int N = in_sizes[0] / DCH;

  unsigned short* WfH = (unsigned short*)d_ws;            // 32 KB
  unsigned short* WfL = WfH + DCH * DCH;                  // 32 KB
  int* seg = (int*)(WfL + DCH * DCH);                     // (SEGS+1)*4 B

  int setup_threads = DCH * DCH + SEGS + 1;
  setup_kernel<<<(setup_threads + 255) / 256, 256, 0, stream>>>(W, idx, N, WfH, WfL, seg);
  pool_kernel<<<SEGS / SEGPB, 256, 0, stream>>>(x, bias, seg,
                                                (const u32x4*)WfH, (const u32x4*)WfL,
                                                (float*)d_out);
}

// Round 8
// 308.249 us; speedup vs baseline: 1.0808x; 1.0152x over previous
//
#include <hip/hip_runtime.h>
#include <hip/hip_bf16.h>

#define SEGS   16384
#define DCH    128
#define CHUNK  32
#define SEGPB  4          // consecutive segments per block
#define HPITCH 136        // plane pitch in shorts (272B): 2-way-max banks, imm-friendly
#define LOG2E  1.4426950408889634f

using f32x4  = __attribute__((ext_vector_type(4))) float;
using bf16x8 = __attribute__((ext_vector_type(8))) short;
using u32x2  = __attribute__((ext_vector_type(2))) unsigned int;
using u32x4  = __attribute__((ext_vector_type(4))) unsigned int;

__device__ __forceinline__ float u2f(unsigned int u) { return __uint_as_float(u); }
__device__ __forceinline__ unsigned int f2u(float f) { return __float_as_uint(f); }

// ---------------------------------------------------------------------------
// Setup: (a) W' = W * log2e -> fragment-ready bf16 hi/lo layout (serves as the
//            MFMA *A* operand: lane = (ch&15) + 16*kgrp holds 8 consecutive k)
//        (b) per-segment row starts via binary search on sorted index
// ---------------------------------------------------------------------------
__global__ void setup_kernel(const float* __restrict__ W,
                             const int* __restrict__ index, int N,
                             unsigned short* __restrict__ WfH,
                             unsigned short* __restrict__ WfL,
                             int* __restrict__ seg_start) {
  int i = blockIdx.x * blockDim.x + threadIdx.x;
  if (i < DCH * DCH) {
    int n = i >> 7, k = i & 127;           // W[n][k], n = channel
    float w = W[i] * LOG2E;                // fold log2e -> raw exp2 in softmax
    unsigned int u = f2u(w);
    unsigned int hu = u & 0xFFFF0000u;     // truncated bf16 hi
    float lo = w - u2f(hu);                // residual -> bf16 lo
    int kt    = k >> 5;
    int ntile = n >> 4;
    int lane  = (n & 15) + 16 * ((k >> 3) & 3);
    int j     = k & 7;
    int dst = ((kt * 8 + ntile) * 64 + lane) * 8 + j;
    WfH[dst] = (unsigned short)(u >> 16);
    WfL[dst] = (unsigned short)(f2u(lo) >> 16);
  } else if (i < DCH * DCH + SEGS + 1) {
    int s = i - DCH * DCH;                 // lower_bound(index, s)
    int lo = 0, hi = N;
    while (lo < hi) {
      int mid = (lo + hi) >> 1;
      if (index[mid] < s) lo = mid + 1; else hi = mid;
    }
    seg_start[s] = lo;
  }
}

// ---------------------------------------------------------------------------
// Main: block b owns segments [4b, 4b+4). 4 waves; wave w owns channels
// [32w, 32w+32). 2-buffer LDS pipeline, one raw s_barrier per chunk; next
// chunk's global loads stay in flight across the barrier.
// SWAPPED MFMA: A = W' (channels x k), B = x^T (k x rows) => C[ch][row] with
// col(lane&15) = x-row, regs = 4 consecutive channels. e*x is a plain
// vectorized row-major LDS read. Linear pad-136 addressing: every LDS access
// is base + compile-time immediate; worst bank aliasing is free 2-way.
// ---------------------------------------------------------------------------
__global__ __launch_bounds__(256) void pool_kernel(
    const float* __restrict__ x, const float* __restrict__ bias,
    const int* __restrict__ seg_start,
    const u32x4* __restrict__ WfH, const u32x4* __restrict__ WfL,
    float* __restrict__ out) {
  __shared__ unsigned short xh[2][CHUNK * HPITCH];
  __shared__ unsigned short xl[2][CHUNK * HPITCH];

  const int t    = threadIdx.x;
  const int wv   = t >> 6;
  const int lane = t & 63;
  const int cl   = lane & 15;              // x-row within 16-tile (C col)
  const int g    = lane >> 4;              // k-group / channel-quad select
  const int lrow = t >> 5;                 // staging: rows 0..7 (+8 per p)
  const int lcol = (t & 31) << 2;          // staging: element col (4-aligned)

  // W' fragments (A operand) for this wave's 32 channels, hi & lo — once.
  u32x4 wh[4][2], wl[4][2];
#pragma unroll
  for (int kt = 0; kt < 4; ++kt)
#pragma unroll
    for (int mt = 0; mt < 2; ++mt) {
      int off = (kt * 8 + (wv * 2 + mt)) * 64 + lane;   // 16B units
      wh[kt][mt] = WfH[off];
      wl[kt][mt] = WfL[off];
    }

  // bias for this lane's 4 channels per mt (broadcast over cl)
  f32x4 bias_v[2];
#pragma unroll
  for (int mt = 0; mt < 2; ++mt) {
    f32x4 b = *(const f32x4*)&bias[wv * 32 + mt * 16 + g * 4];
#pragma unroll
    for (int c = 0; c < 4; ++c) bias_v[mt][c] = b[c] * LOG2E;
  }

  const int s0   = blockIdx.x * SEGPB;
  const int sEnd = s0 + SEGPB;

  // Empty segments (rare): zeros, outside the pipeline.
  for (int es = s0; es < sEnd; ++es) {
    if (seg_start[es + 1] == seg_start[es] && cl == 0) {
#pragma unroll
      for (int mt = 0; mt < 2; ++mt)
        *(f32x4*)&out[(size_t)es * DCH + wv * 32 + mt * 16 + g * 4] =
            (f32x4){0.f, 0.f, 0.f, 0.f};
    }
  }

  int s = s0;
  while (s < sEnd && seg_start[s + 1] == seg_start[s]) ++s;
  if (s >= sEnd) return;                   // whole block empty (uniform exit)

  int c0  = 0;
  int len = seg_start[s + 1] - seg_start[s];
  int cnt = (len < CHUNK) ? len : CHUNK;

  // Prefetch first chunk into registers (rows >= cnt zero-filled).
  f32x4 pv[4];
  {
    const int base = seg_start[s];
#pragma unroll
    for (int p = 0; p < 4; ++p) {
      int lr = lrow + p * 8;
      f32x4 v = {0.f, 0.f, 0.f, 0.f};
      if (lr < cnt) v = *(const f32x4*)(x + (size_t)(base + lr) * DCH + lcol);
      pv[p] = v;
    }
  }

  f32x4 num_v[2], den_v[2];                // [mt], elements = 4 channels
#pragma unroll
  for (int mt = 0; mt < 2; ++mt) {
    num_v[mt] = (f32x4){0.f, 0.f, 0.f, 0.f};
    den_v[mt] = (f32x4){0.f, 0.f, 0.f, 0.f};
  }
  int buf = 0;

  while (true) {
    // ---- next-chunk coordinates (wave-uniform scalar work) ----
    int ns = s, nc0 = c0 + CHUNK;
    if (nc0 >= len) {
      nc0 = 0; ns = s + 1;
      while (ns < sEnd && seg_start[ns + 1] == seg_start[ns]) ++ns;
    }
    const bool have_next = (ns < sEnd);
    int nlen = 0, ncnt = 0, nbase = 0;
    if (have_next) {
      nbase = seg_start[ns] + nc0;
      nlen  = seg_start[ns + 1] - seg_start[ns];
      ncnt  = nlen - nc0; if (ncnt > CHUNK) ncnt = CHUNK;
    }

    // ---- convert prefetched regs -> LDS planes (vmcnt wait lands here) ----
    unsigned short* XH = &xh[buf][0];
    unsigned short* XL = &xl[buf][0];
    {
      const int sbase = lrow * HPITCH + lcol;   // + p*8*HPITCH as immediate
#pragma unroll
      for (int p = 0; p < 4; ++p) {
        f32x4 v = pv[p];
        unsigned int u0 = f2u(v[0]), u1 = f2u(v[1]), u2 = f2u(v[2]), u3 = f2u(v[3]);
        unsigned int h0 = u0 & 0xFFFF0000u, h1 = u1 & 0xFFFF0000u;
        unsigned int h2 = u2 & 0xFFFF0000u, h3 = u3 & 0xFFFF0000u;
        float l0f = v[0] - u2f(h0), l1f = v[1] - u2f(h1);
        float l2f = v[2] - u2f(h2), l3f = v[3] - u2f(h3);
        u32x2 H = { h1 | (u0 >> 16), h3 | (u2 >> 16) };
        u32x2 L = { (f2u(l1f) & 0xFFFF0000u) | (f2u(l0f) >> 16),
                    (f2u(l3f) & 0xFFFF0000u) | (f2u(l2f) >> 16) };
        *(u32x2*)&XH[sbase + p * 8 * HPITCH] = H;
        *(u32x2*)&XL[sbase + p * 8 * HPITCH] = L;
      }
    }

    // ---- issue next chunk's global loads (in flight through MFMA phase) ----
    if (have_next) {
#pragma unroll
      for (int p = 0; p < 4; ++p) {
        int lr = lrow + p * 8;
        f32x4 v = {0.f, 0.f, 0.f, 0.f};
        if (lr < ncnt) v = *(const f32x4*)(x + (size_t)(nbase + lr) * DCH + lcol);
        pv[p] = v;
      }
    }

    // ---- single barrier: planes of buf ready; prefetch NOT drained ----
    asm volatile("s_waitcnt lgkmcnt(0)" ::: "memory");
    __builtin_amdgcn_sched_barrier(0);
    __builtin_amdgcn_s_barrier();
    __builtin_amdgcn_sched_barrier(0);

    // ---- att'^T = W' x^T + b' : C[ch][row], this wave's 32 channels ----
    f32x4 Cf[2][2];                        // [mt(ch)][nt(row)]
#pragma unroll
    for (int mt = 0; mt < 2; ++mt)
#pragma unroll
      for (int nt = 0; nt < 2; ++nt)
        Cf[mt][nt] = bias_v[mt];

    {
      const int fbase = cl * HPITCH + g * 8;   // + nt*16*HPITCH + kt*32 as imm
#pragma unroll
      for (int kt = 0; kt < 4; ++kt) {
        u32x4 xbh[2], xbl[2];              // x^T B-frags per nt (row tile)
#pragma unroll
        for (int nt = 0; nt < 2; ++nt) {
          int ai = fbase + nt * 16 * HPITCH + kt * 32;
          xbh[nt] = *(const u32x4*)&XH[ai];
          xbl[nt] = *(const u32x4*)&XL[ai];
        }
#pragma unroll
        for (int sp = 0; sp < 3; ++sp)     // (Wh,xh), (Wl,xh), (Wh,xl)
#pragma unroll
          for (int mt = 0; mt < 2; ++mt)
#pragma unroll
            for (int nt = 0; nt < 2; ++nt) {
              bf16x8 A = __builtin_bit_cast(bf16x8, (sp == 1) ? wl[kt][mt] : wh[kt][mt]);
              bf16x8 B = __builtin_bit_cast(bf16x8, (sp == 2) ? xbl[nt] : xbh[nt]);
              Cf[mt][nt] = __builtin_amdgcn_mfma_f32_16x16x32_bf16(A, B, Cf[mt][nt], 0, 0, 0);
            }
      }
    }

    // ---- e = exp2(att'); vectorized e*x accumulate (all lane-local) ----
    // C layout: col(lane&15) = x-row, reg r = channel mt*16 + g*4 + r
    {
      const int ebase = cl * HPITCH + wv * 32 + g * 4;  // + nt*16*HPITCH + mt*16
#pragma unroll
      for (int nt = 0; nt < 2; ++nt) {
        const int row = nt * 16 + cl;
        if (row < cnt) {
#pragma unroll
          for (int mt = 0; mt < 2; ++mt) {
            const int di = ebase + nt * 16 * HPITCH + mt * 16;
            u32x2 hv = *(const u32x2*)&XH[di];
            u32x2 lv = *(const u32x2*)&XL[di];
            float x0 = u2f(hv[0] << 16)         + u2f(lv[0] << 16);
            float x1 = u2f(hv[0] & 0xFFFF0000u) + u2f(lv[0] & 0xFFFF0000u);
            float x2 = u2f(hv[1] << 16)         + u2f(lv[1] << 16);
            float x3 = u2f(hv[1] & 0xFFFF0000u) + u2f(lv[1] & 0xFFFF0000u);
            float p0 = __builtin_amdgcn_exp2f(Cf[mt][nt][0]);
            float p1 = __builtin_amdgcn_exp2f(Cf[mt][nt][1]);
            float p2 = __builtin_amdgcn_exp2f(Cf[mt][nt][2]);
            float p3 = __builtin_amdgcn_exp2f(Cf[mt][nt][3]);
            den_v[mt][0] += p0; num_v[mt][0] += p0 * x0;
            den_v[mt][1] += p1; num_v[mt][1] += p1 * x1;
            den_v[mt][2] += p2; num_v[mt][2] += p2 * x2;
            den_v[mt][3] += p3; num_v[mt][3] += p3 * x3;
          }
        }
      }
    }

    // ---- segment bookkeeping ----
    if (c0 + CHUNK >= len) {               // segment s complete -> store
#pragma unroll
      for (int mt = 0; mt < 2; ++mt) {
#pragma unroll
        for (int c = 0; c < 4; ++c) {      // butterfly over cl (rows)
          num_v[mt][c] += __shfl_xor(num_v[mt][c], 1);
          den_v[mt][c] += __shfl_xor(den_v[mt][c], 1);
          num_v[mt][c] += __shfl_xor(num_v[mt][c], 2);
          den_v[mt][c] += __shfl_xor(den_v[mt][c], 2);
          num_v[mt][c] += __shfl_xor(num_v[mt][c], 4);
          den_v[mt][c] += __shfl_xor(den_v[mt][c], 4);
          num_v[mt][c] += __shfl_xor(num_v[mt][c], 8);
          den_v[mt][c] += __shfl_xor(den_v[mt][c], 8);
        }
        if (cl == 0) {
          f32x4 o;
#pragma unroll
          for (int c = 0; c < 4; ++c) o[c] = num_v[mt][c] / (den_v[mt][c] + 1e-16f);
          *(f32x4*)&out[(size_t)s * DCH + wv * 32 + mt * 16 + g * 4] = o;
        }
        num_v[mt] = (f32x4){0.f, 0.f, 0.f, 0.f};
        den_v[mt] = (f32x4){0.f, 0.f, 0.f, 0.f};
      }
      if (!have_next) break;
      s = ns; len = nlen; c0 = 0;
    } else {
      c0 = nc0;
    }
    cnt = ncnt;
    buf ^= 1;
  }
}

extern "C" void kernel_launch(void* const* d_in, const int* in_sizes, int n_in,
                              void* d_out, int out_size, void* d_ws, size_t ws_size,
                              hipStream_t stream) {
  const float* x    = (const float*)d_in[0];
  const float* W    = (const float*)d_in[1];
  const float* bias = (const float*)d_in[2];
  const int*   idx  = (const int*)d_in[3];
  const int N = in_sizes[0] / DCH;

  unsigned short* WfH = (unsigned short*)d_ws;            // 32 KB
  unsigned short* WfL = WfH + DCH * DCH;                  // 32 KB
  int* seg = (int*)(WfL + DCH * DCH);                     // (SEGS+1)*4 B

  int setup_threads = DCH * DCH + SEGS + 1;
  setup_kernel<<<(setup_threads + 255) / 256, 256, 0, stream>>>(W, idx, N, WfH, WfL, seg);
  pool_kernel<<<SEGS / SEGPB, 256, 0, stream>>>(x, bias, seg,
                                                (const u32x4*)WfH, (const u32x4*)WfL,
                                                (float*)d_out);
}

// Round 9
// 172.667 us; speedup vs baseline: 1.9295x; 1.7852x over previous
//
#include <hip/hip_runtime.h>
#include <hip/hip_bf16.h>

#define SEGS   16384
#define DCH    128
#define CHUNK  32
#define SEGPB  4          // consecutive segments per block
#define HPITCH 136        // bf16 plane pitch (shorts) = 272B
#define LOG2E  1.4426950408889634f

using f32x4  = __attribute__((ext_vector_type(4))) float;
using bf16x8 = __attribute__((ext_vector_type(8))) short;
using u32x2  = __attribute__((ext_vector_type(2))) unsigned int;
using u32x4  = __attribute__((ext_vector_type(4))) unsigned int;

__device__ __forceinline__ float u2f(unsigned int u) { return __uint_as_float(u); }
__device__ __forceinline__ unsigned int f2u(float f) { return __float_as_uint(f); }

// ---------------------------------------------------------------------------
// Setup: (a) W' = W * log2e -> fragment-ready bf16 (round-to-nearest) B layout
//        (b) per-segment row starts via binary search on sorted index
// ---------------------------------------------------------------------------
__global__ void setup_kernel(const float* __restrict__ W,
                             const int* __restrict__ index, int N,
                             unsigned short* __restrict__ WfH,
                             int* __restrict__ seg_start) {
  int i = blockIdx.x * blockDim.x + threadIdx.x;
  if (i < DCH * DCH) {
    int n = i >> 7, k = i & 127;           // W[n][k]
    float w = W[i] * LOG2E;                // fold log2e -> raw exp2 in softmax
    // round-to-nearest-even bf16 (better than truncation for single-MFMA)
    unsigned int u = f2u(w);
    unsigned int r = (u + 0x7FFFu + ((u >> 16) & 1)) >> 16;
    int kt    = k >> 5;
    int ntile = n >> 4;
    int lane  = (n & 15) + 16 * ((k >> 3) & 3);
    int j     = k & 7;
    int dst = ((kt * 8 + ntile) * 64 + lane) * 8 + j;
    WfH[dst] = (unsigned short)r;
  } else if (i < DCH * DCH + SEGS + 1) {
    int s = i - DCH * DCH;                 // lower_bound(index, s)
    int lo = 0, hi = N;
    while (lo < hi) {
      int mid = (lo + hi) >> 1;
      if (index[mid] < s) lo = mid + 1; else hi = mid;
    }
    seg_start[s] = lo;
  }
}

// ---------------------------------------------------------------------------
// Main: block b owns segments [4b, 4b+4). 4 waves; wave w owns channels
// [32w, 32w+32). 2-buffer LDS pipeline, one raw s_barrier per chunk; next
// chunk's global loads stay in flight across the barrier. x staged as bf16
// hi/lo planes (exact reconstruction in e*x); MFMA is single-pass bf16
// (A = x_hi, B = W_bf16) — error analysis: att err sigma ~1e-3, output
// contribution ~2e-3 << 1.76e-2 threshold.
// ---------------------------------------------------------------------------
__global__ __launch_bounds__(256) void pool_kernel(
    const float* __restrict__ x, const float* __restrict__ bias,
    const int* __restrict__ seg_start,
    const u32x4* __restrict__ WfH,
    float* __restrict__ out) {
  __shared__ unsigned short xh[2][CHUNK * HPITCH];
  __shared__ unsigned short xl[2][CHUNK * HPITCH];

  const int t    = threadIdx.x;
  const int wv   = t >> 6;
  const int lane = t & 63;
  const int cl   = lane & 15;              // A-row sel / C col within 16-tile
  const int g    = lane >> 4;              // lane group (k-slice / row group)
  const int lrow = t >> 5;                 // staging: rows 0..7 (+8 per p)
  const int lcol = (t & 31) << 2;          // staging: f32x4 col

  // Register-resident B fragments (this wave's 32 channels) — hi only.
  u32x4 bh[4][2];
#pragma unroll
  for (int kt = 0; kt < 4; ++kt)
#pragma unroll
    for (int nt = 0; nt < 2; ++nt) {
      int off = (kt * 8 + (wv * 2 + nt)) * 64 + lane;   // 16B units
      bh[kt][nt] = WfH[off];
    }

  const float bc0 = bias[wv * 32 + cl]      * LOG2E;
  const float bc1 = bias[wv * 32 + 16 + cl] * LOG2E;

  const int s0   = blockIdx.x * SEGPB;
  const int sEnd = s0 + SEGPB;

  // Empty segments (rare): write zeros outside the pipeline, keep CF uniform.
  for (int es = s0; es < sEnd; ++es) {
    if (seg_start[es + 1] == seg_start[es] && lane < 16) {
      out[(size_t)es * DCH + wv * 32 + cl]      = 0.f;
      out[(size_t)es * DCH + wv * 32 + 16 + cl] = 0.f;
    }
  }

  int s = s0;
  while (s < sEnd && seg_start[s + 1] == seg_start[s]) ++s;
  if (s >= sEnd) return;                   // whole block empty (uniform exit)

  int c0  = 0;
  int len = seg_start[s + 1] - seg_start[s];
  int cnt = (len < CHUNK) ? len : CHUNK;

  // Prefetch first chunk into registers (rows >= cnt zero-filled).
  f32x4 pv[4];
  {
    const int base = seg_start[s];
#pragma unroll
    for (int p = 0; p < 4; ++p) {
      int lr = lrow + p * 8;
      f32x4 v = {0.f, 0.f, 0.f, 0.f};
      if (lr < cnt) v = *(const f32x4*)(x + (size_t)(base + lr) * DCH + lcol);
      pv[p] = v;
    }
  }

  float den[2] = {0.f, 0.f};
  float num[2] = {0.f, 0.f};
  int buf = 0;

  while (true) {
    // ---- next-chunk coordinates (wave-uniform scalar work) ----
    int ns = s, nc0 = c0 + CHUNK;
    if (nc0 >= len) {
      nc0 = 0; ns = s + 1;
      while (ns < sEnd && seg_start[ns + 1] == seg_start[ns]) ++ns;
    }
    const bool have_next = (ns < sEnd);
    int nlen = 0, ncnt = 0, nbase = 0;
    if (have_next) {
      nbase = seg_start[ns] + nc0;
      nlen  = seg_start[ns + 1] - seg_start[ns];
      ncnt  = nlen - nc0; if (ncnt > CHUNK) ncnt = CHUNK;
    }

    // ---- convert prefetched regs -> LDS planes buf (vmcnt wait lands here) --
    unsigned short* XH = &xh[buf][0];
    unsigned short* XL = &xl[buf][0];
#pragma unroll
    for (int p = 0; p < 4; ++p) {
      int lr = lrow + p * 8;
      f32x4 v = pv[p];
      unsigned int u0 = f2u(v[0]), u1 = f2u(v[1]), u2 = f2u(v[2]), u3 = f2u(v[3]);
      unsigned int h0 = u0 & 0xFFFF0000u, h1 = u1 & 0xFFFF0000u;
      unsigned int h2 = u2 & 0xFFFF0000u, h3 = u3 & 0xFFFF0000u;
      float l0f = v[0] - u2f(h0), l1f = v[1] - u2f(h1);
      float l2f = v[2] - u2f(h2), l3f = v[3] - u2f(h3);
      u32x2 H = { h1 | (u0 >> 16), h3 | (u2 >> 16) };
      u32x2 L = { (f2u(l1f) & 0xFFFF0000u) | (f2u(l0f) >> 16),
                  (f2u(l3f) & 0xFFFF0000u) | (f2u(l2f) >> 16) };
      *(u32x2*)&XH[lr * HPITCH + lcol] = H;
      *(u32x2*)&XL[lr * HPITCH + lcol] = L;
    }

    // ---- issue next chunk's global loads (in flight through MFMA phase) ----
    if (have_next) {
#pragma unroll
      for (int p = 0; p < 4; ++p) {
        int lr = lrow + p * 8;
        f32x4 v = {0.f, 0.f, 0.f, 0.f};
        if (lr < ncnt) v = *(const f32x4*)(x + (size_t)(nbase + lr) * DCH + lcol);
        pv[p] = v;
      }
    }

    // ---- single barrier: planes of buf ready; prefetch NOT drained ----
    asm volatile("s_waitcnt lgkmcnt(0)" ::: "memory");
    __builtin_amdgcn_sched_barrier(0);
    __builtin_amdgcn_s_barrier();
    __builtin_amdgcn_sched_barrier(0);

    // ---- att' = (x @ W'^T + b') for this chunk (this wave's 32 cols) ----
    f32x4 Cf[2][2];
#pragma unroll
    for (int mt = 0; mt < 2; ++mt) {
      Cf[mt][0] = (f32x4){bc0, bc0, bc0, bc0};
      Cf[mt][1] = (f32x4){bc1, bc1, bc1, bc1};
    }

#pragma unroll
    for (int kt = 0; kt < 4; ++kt) {
      u32x4 ah[2];
#pragma unroll
      for (int mt = 0; mt < 2; ++mt) {
        const unsigned short* p0 = &XH[(mt * 16 + cl) * HPITCH + kt * 32 + g * 8];
        ah[mt] = *(const u32x4*)p0;
      }
#pragma unroll
      for (int mt = 0; mt < 2; ++mt)
#pragma unroll
        for (int nt = 0; nt < 2; ++nt) {
          bf16x8 A = __builtin_bit_cast(bf16x8, ah[mt]);
          bf16x8 B = __builtin_bit_cast(bf16x8, bh[kt][nt]);
          Cf[mt][nt] = __builtin_amdgcn_mfma_f32_16x16x32_bf16(A, B, Cf[mt][nt], 0, 0, 0);
        }
    }

    // ---- e = exp2(att'); accumulate den/num (no max: |att'| bounded) ----
    // C layout: col = lane&15, row(in 16-tile) = g*4 + reg   [m89/m91]
#pragma unroll
    for (int nt = 0; nt < 2; ++nt) {
      const int cidx = wv * 32 + nt * 16 + cl;
#pragma unroll
      for (int mt = 0; mt < 2; ++mt)
#pragma unroll
        for (int r = 0; r < 4; ++r) {
          int row = mt * 16 + g * 4 + r;
          if (row < cnt) {
            float p = __builtin_amdgcn_exp2f(Cf[mt][nt][r]);
            unsigned int hv = XH[row * HPITCH + cidx];
            unsigned int lv = XL[row * HPITCH + cidx];
            float xv = u2f(hv << 16) + u2f(lv << 16);
            den[nt] += p;
            num[nt] += p * xv;
          }
        }
    }

    // ---- segment bookkeeping ----
    if (c0 + CHUNK >= len) {               // segment s complete -> store
#pragma unroll
      for (int nt = 0; nt < 2; ++nt) {
        float l = den[nt], a = num[nt];
        l += __shfl_xor(l, 16); l += __shfl_xor(l, 32);
        a += __shfl_xor(a, 16); a += __shfl_xor(a, 32);
        if (lane < 16)
          out[(size_t)s * DCH + wv * 32 + nt * 16 + cl] = a / (l + 1e-16f);
        den[nt] = 0.f; num[nt] = 0.f;
      }
      if (!have_next) break;
      s = ns; len = nlen; c0 = 0;
    } else {
      c0 = nc0;
    }
    cnt = ncnt;
    buf ^= 1;
  }
}

extern "C" void kernel_launch(void* const* d_in, const int* in_sizes, int n_in,
                              void* d_out, int out_size, void* d_ws, size_t ws_size,
                              hipStream_t stream) {
  const float* x    = (const float*)d_in[0];
  const float* W    = (const float*)d_in[1];
  const float* bias = (const float*)d_in[2];
  const int*   idx  = (const int*)d_in[3];
  const int N = in_sizes[0] / DCH;

  unsigned short* WfH = (unsigned short*)d_ws;            // 32 KB
  int* seg = (int*)(WfH + DCH * DCH);                     // (SEGS+1)*4 B

  int setup_threads = DCH * DCH + SEGS + 1;
  setup_kernel<<<(setup_threads + 255) / 256, 256, 0, stream>>>(W, idx, N, WfH, seg);
  pool_kernel<<<SEGS / SEGPB, 256, 0, stream>>>(x, bias, seg,
                                                (const u32x4*)WfH,
                                                (float*)d_out);
}

// Round 10
// 125.121 us; speedup vs baseline: 2.6628x; 1.3800x over previous
//
#include <hip/hip_runtime.h>
#include <hip/hip_bf16.h>

#define SEGS   16384
#define DCH    128
#define CHUNK  32
#define SEGPB  4          // consecutive segments per block
#define FPITCH 132        // f32 plane pitch (528B rows, 16B-aligned, 2-way max)
#define XHBLK  520        // frag-layout block stride in shorts (8 blocks of 512+8 pad)
#define LOG2E  1.4426950408889634f

using f32x4  = __attribute__((ext_vector_type(4))) float;
using bf16x8 = __attribute__((ext_vector_type(8))) short;
using u32x2  = __attribute__((ext_vector_type(2))) unsigned int;
using u32x4  = __attribute__((ext_vector_type(4))) unsigned int;

__device__ __forceinline__ float u2f(unsigned int u) { return __uint_as_float(u); }
__device__ __forceinline__ unsigned int f2u(float f) { return __float_as_uint(f); }

// ---------------------------------------------------------------------------
// Setup: (a) W' = W * log2e -> fragment-ready bf16 (RTNE) B layout
//        (b) per-segment row starts via binary search on sorted index
// ---------------------------------------------------------------------------
__global__ void setup_kernel(const float* __restrict__ W,
                             const int* __restrict__ index, int N,
                             unsigned short* __restrict__ WfH,
                             int* __restrict__ seg_start) {
  int i = blockIdx.x * blockDim.x + threadIdx.x;
  if (i < DCH * DCH) {
    int n = i >> 7, k = i & 127;           // W[n][k]
    float w = W[i] * LOG2E;                // fold log2e -> raw exp2 in softmax
    unsigned int u = f2u(w);
    unsigned int r = (u + 0x7FFFu + ((u >> 16) & 1)) >> 16;  // RTNE bf16
    int kt    = k >> 5;
    int ntile = n >> 4;
    int lane  = (n & 15) + 16 * ((k >> 3) & 3);
    int j     = k & 7;
    int dst = ((kt * 8 + ntile) * 64 + lane) * 8 + j;
    WfH[dst] = (unsigned short)r;
  } else if (i < DCH * DCH + SEGS + 1) {
    int s = i - DCH * DCH;                 // lower_bound(index, s)
    int lo = 0, hi = N;
    while (lo < hi) {
      int mid = (lo + hi) >> 1;
      if (index[mid] < s) lo = mid + 1; else hi = mid;
    }
    seg_start[s] = lo;
  }
}

// ---------------------------------------------------------------------------
// Main: block b owns segments [4b, 4b+4). 4 waves; wave w owns channels
// [32w, 32w+32). Single-buffered LDS, 2 raw barriers/chunk; next chunk's
// global loads stay in flight across BOTH barriers (no vmcnt drain).
// LDS: xh = x_hi in MFMA-FRAGMENT layout [kt][rowtile][lane][8] (+pad):
//      staging writes b64 @ imm offsets; frag reads are dense b128 at
//      lane*16 + imm (no conflicts, no address VALU).
//      xf = exact f32 x plane for the e*x accumulation (16 b32 reads, 2-way).
// ---------------------------------------------------------------------------
__global__ __launch_bounds__(256) void pool_kernel(
    const float* __restrict__ x, const float* __restrict__ bias,
    const int* __restrict__ seg_start,
    const u32x4* __restrict__ WfH,
    float* __restrict__ out) {
  __shared__ unsigned short xh[8 * XHBLK];      // 8.32 KB
  __shared__ float          xf[CHUNK * FPITCH]; // 16.9 KB

  const int t    = threadIdx.x;
  const int wv   = t >> 6;
  const int lane = t & 63;
  const int cl   = lane & 15;              // C col within 16-tile (channel)
  const int g    = lane >> 4;              // lane group (k-slice / row group)
  const int k31  = t & 31;                 // staging lane-in-phase
  const int lrow = t >> 5;                 // staging rows 0..7 (+8 per p)
  const int lcol = k31 << 2;               // staging col (4 floats)

  // staging bases (constant per thread)
  const int xh_base = 1040 * (k31 >> 3) + 8 * lrow + 128 * ((k31 >> 1) & 3) + 4 * (k31 & 1);
  const int xf_base = lrow * FPITCH + lcol;
  // compute-phase bases
  const int frag_base = lane * 8;                    // shorts
  const int ex_base   = g * 4 * FPITCH + wv * 32 + cl;

  // Register-resident W fragments (this wave's 32 channels).
  u32x4 bh[4][2];
#pragma unroll
  for (int kt = 0; kt < 4; ++kt)
#pragma unroll
    for (int nt = 0; nt < 2; ++nt) {
      int off = (kt * 8 + (wv * 2 + nt)) * 64 + lane;   // 16B units
      bh[kt][nt] = WfH[off];
    }

  const float bc0 = bias[wv * 32 + cl]      * LOG2E;
  const float bc1 = bias[wv * 32 + 16 + cl] * LOG2E;

  const int s0   = blockIdx.x * SEGPB;
  const int sEnd = s0 + SEGPB;

  // Empty segments (rare): write zeros outside the pipeline, keep CF uniform.
  for (int es = s0; es < sEnd; ++es) {
    if (seg_start[es + 1] == seg_start[es] && lane < 16) {
      out[(size_t)es * DCH + wv * 32 + cl]      = 0.f;
      out[(size_t)es * DCH + wv * 32 + 16 + cl] = 0.f;
    }
  }

  int s = s0;
  while (s < sEnd && seg_start[s + 1] == seg_start[s]) ++s;
  if (s >= sEnd) return;                   // whole block empty (uniform exit)

  int c0  = 0;
  int len = seg_start[s + 1] - seg_start[s];
  int cnt = (len < CHUNK) ? len : CHUNK;

  // Prefetch first chunk into registers (rows >= cnt zero-filled).
  f32x4 pv[4];
  {
    const int base = seg_start[s];
#pragma unroll
    for (int p = 0; p < 4; ++p) {
      int lr = lrow + p * 8;
      f32x4 v = {0.f, 0.f, 0.f, 0.f};
      if (lr < cnt) v = *(const f32x4*)(x + (size_t)(base + lr) * DCH + lcol);
      pv[p] = v;
    }
  }

  float den[2] = {0.f, 0.f};
  float num[2] = {0.f, 0.f};

  while (true) {
    // ---- next-chunk coordinates (wave-uniform scalar work) ----
    int ns = s, nc0 = c0 + CHUNK;
    if (nc0 >= len) {
      nc0 = 0; ns = s + 1;
      while (ns < sEnd && seg_start[ns + 1] == seg_start[ns]) ++ns;
    }
    const bool have_next = (ns < sEnd);
    int nlen = 0, ncnt = 0, nbase = 0;
    if (have_next) {
      nbase = seg_start[ns] + nc0;
      nlen  = seg_start[ns + 1] - seg_start[ns];
      ncnt  = nlen - nc0; if (ncnt > CHUNK) ncnt = CHUNK;
    }

    // ---- PHASE W: convert pv -> xh (frag layout) + xf (f32 plane) ----
#pragma unroll
    for (int p = 0; p < 4; ++p) {
      f32x4 v = pv[p];
      unsigned int u0 = f2u(v[0]), u1 = f2u(v[1]), u2 = f2u(v[2]), u3 = f2u(v[3]);
      u32x2 H = { (u1 & 0xFFFF0000u) | (u0 >> 16),
                  (u3 & 0xFFFF0000u) | (u2 >> 16) };
      *(u32x2*)&xh[xh_base + (p >> 1) * XHBLK + (p & 1) * 64] = H;
      *(f32x4*)&xf[xf_base + p * 8 * FPITCH] = v;
    }

    // ---- issue next chunk's global loads (in flight through both barriers) --
    if (have_next) {
#pragma unroll
      for (int p = 0; p < 4; ++p) {
        int lr = lrow + p * 8;
        f32x4 v = {0.f, 0.f, 0.f, 0.f};
        if (lr < ncnt) v = *(const f32x4*)(x + (size_t)(nbase + lr) * DCH + lcol);
        pv[p] = v;
      }
    }

    // ---- barrier A: LDS writes visible; prefetch NOT drained ----
    asm volatile("s_waitcnt lgkmcnt(0)" ::: "memory");
    __builtin_amdgcn_sched_barrier(0);
    __builtin_amdgcn_s_barrier();
    __builtin_amdgcn_sched_barrier(0);

    // ---- PHASE R: att' = x @ W'^T + b' (this wave's 32 channels) ----
    f32x4 Cf[2][2];
#pragma unroll
    for (int mt = 0; mt < 2; ++mt) {
      Cf[mt][0] = (f32x4){bc0, bc0, bc0, bc0};
      Cf[mt][1] = (f32x4){bc1, bc1, bc1, bc1};
    }

#pragma unroll
    for (int kt = 0; kt < 4; ++kt) {
      u32x4 ah[2];
#pragma unroll
      for (int mt = 0; mt < 2; ++mt)
        ah[mt] = *(const u32x4*)&xh[frag_base + (2 * kt + mt) * XHBLK];
#pragma unroll
      for (int mt = 0; mt < 2; ++mt)
#pragma unroll
        for (int nt = 0; nt < 2; ++nt) {
          bf16x8 A = __builtin_bit_cast(bf16x8, ah[mt]);
          bf16x8 B = __builtin_bit_cast(bf16x8, bh[kt][nt]);
          Cf[mt][nt] = __builtin_amdgcn_mfma_f32_16x16x32_bf16(A, B, Cf[mt][nt], 0, 0, 0);
        }
    }

    // ---- e = exp2(att'); e*x from exact f32 plane (16 b32 reads) ----
    // C layout: col = lane&15 (channel), row(in 16-tile) = g*4 + reg  [m89/m91]
#pragma unroll
    for (int nt = 0; nt < 2; ++nt) {
#pragma unroll
      for (int mt = 0; mt < 2; ++mt)
#pragma unroll
        for (int r = 0; r < 4; ++r) {
          const int row = mt * 16 + g * 4 + r;
          float p = __builtin_amdgcn_exp2f(Cf[mt][nt][r]);
          p = (row < cnt) ? p : 0.f;
          float xv = xf[ex_base + (mt * 16 + r) * FPITCH + nt * 16];
          den[nt] += p;
          num[nt] += p * xv;
        }
    }

    // ---- segment bookkeeping ----
    if (c0 + CHUNK >= len) {               // segment s complete -> store
#pragma unroll
      for (int nt = 0; nt < 2; ++nt) {
        float l = den[nt], a = num[nt];
        l += __shfl_xor(l, 16); l += __shfl_xor(l, 32);
        a += __shfl_xor(a, 16); a += __shfl_xor(a, 32);
        if (lane < 16)
          out[(size_t)s * DCH + wv * 32 + nt * 16 + cl] = a / (l + 1e-16f);
        den[nt] = 0.f; num[nt] = 0.f;
      }
      if (!have_next) break;
      s = ns; len = nlen; c0 = 0;
    } else {
      c0 = nc0;
    }
    cnt = ncnt;

    // ---- barrier B: all reads of this chunk done -> buffer reusable ----
    asm volatile("s_waitcnt lgkmcnt(0)" ::: "memory");
    __builtin_amdgcn_sched_barrier(0);
    __builtin_amdgcn_s_barrier();
    __builtin_amdgcn_sched_barrier(0);
  }
}

extern "C" void kernel_launch(void* const* d_in, const int* in_sizes, int n_in,
                              void* d_out, int out_size, void* d_ws, size_t ws_size,
                              hipStream_t stream) {
  const float* x    = (const float*)d_in[0];
  const float* W    = (const float*)d_in[1];
  const float* bias = (const float*)d_in[2];
  const int*   idx  = (const int*)d_in[3];
  const int N = in_sizes[0] / DCH;

  unsigned short* WfH = (unsigned short*)d_ws;            // 32 KB
  int* seg = (int*)(WfH + DCH * DCH);                     // (SEGS+1)*4 B

  int setup_threads = DCH * DCH + SEGS + 1;
  setup_kernel<<<(setup_threads + 255) / 256, 256, 0, stream>>>(W, idx, N, WfH, seg);
  pool_kernel<<<SEGS / SEGPB, 256, 0, stream>>>(x, bias, seg,
                                                (const u32x4*)WfH,
                                                (float*)d_out);
}